// Round 1
// baseline (707.535 us; speedup 1.0000x reference)
//
#include <hip/hip_runtime.h>

#define NN 50000
#define EE 800000
#define ET 850000          // EE + NN self-loops
#define NEG 0.2f

__device__ __forceinline__ float leaky(float x) { return x > 0.f ? x : NEG * x; }
__device__ __forceinline__ float elu_f(float x) { return x > 0.f ? x : expm1f(x); }

// ---------------- CSR build (by destination) ----------------
__global__ void hist_k(const int* __restrict__ ei, int* __restrict__ counts) {
    int i = blockIdx.x * blockDim.x + threadIdx.x;
    if (i >= ET) return;
    int dst = (i < EE) ? ei[EE + i] : (i - EE);
    atomicAdd(&counts[dst], 1);
}

__global__ void scan_k(const int* __restrict__ counts, int* __restrict__ rp) {
    __shared__ int tmp[256];
    __shared__ int carry_s;
    if (threadIdx.x == 0) carry_s = 0;
    __syncthreads();
    for (int base = 0; base < NN; base += 256) {
        int i = base + threadIdx.x;
        int v = (i < NN) ? counts[i] : 0;
        tmp[threadIdx.x] = v;
        __syncthreads();
        for (int off = 1; off < 256; off <<= 1) {
            int t = (threadIdx.x >= off) ? tmp[threadIdx.x - off] : 0;
            __syncthreads();
            tmp[threadIdx.x] += t;
            __syncthreads();
        }
        int incl = tmp[threadIdx.x];
        if (i < NN) rp[i] = incl - v + carry_s;   // exclusive
        __syncthreads();
        if (threadIdx.x == 255) carry_s += tmp[255];
        __syncthreads();
    }
    if (threadIdx.x == 0) rp[NN] = carry_s;
}

__global__ void scatter_k(const int* __restrict__ ei, const int* __restrict__ rp,
                          int* __restrict__ fill, int* __restrict__ csr) {
    int i = blockIdx.x * blockDim.x + threadIdx.x;
    if (i >= ET) return;
    int src, dst;
    if (i < EE) { src = ei[i]; dst = ei[EE + i]; }
    else        { src = dst = i - EE; }
    int pos = rp[dst] + atomicAdd(&fill[dst], 1);
    csr[pos] = src;
}

// ---------------- GEMM: [nrows,128] @ [128,128] ----------------
__global__ __launch_bounds__(256, 2)
void gemm128_k(const float* __restrict__ X, const float* __restrict__ W,
               float* __restrict__ Y, int nrows) {
    __shared__ __align__(16) float Wl[128 * 128];   // 64 KB
    __shared__ __align__(16) float Xs[32 * 128];    // 16 KB
    for (int i = threadIdx.x; i < 128 * 128 / 4; i += 256)
        ((float4*)Wl)[i] = ((const float4*)W)[i];

    int tc = threadIdx.x & 31;   // col group -> cols tc*4 .. tc*4+3
    int tr = threadIdx.x >> 5;   // row group -> rows tr*4 .. tr*4+3

    for (int row0 = blockIdx.x * 32; row0 < nrows; row0 += gridDim.x * 32) {
        __syncthreads();   // protect Xs (and initial Wl load)
        for (int i = threadIdx.x; i < 32 * 128 / 4; i += 256) {
            int r = i >> 5, c4 = i & 31;
            int row = row0 + r;
            float4 v = (row < nrows) ? ((const float4*)(X + (size_t)row * 128))[c4]
                                     : make_float4(0.f, 0.f, 0.f, 0.f);
            ((float4*)Xs)[i] = v;
        }
        __syncthreads();

        float acc[4][4] = {};
        for (int k = 0; k < 128; k += 4) {
            float4 w0 = ((float4*)(Wl + (k + 0) * 128))[tc];
            float4 w1 = ((float4*)(Wl + (k + 1) * 128))[tc];
            float4 w2 = ((float4*)(Wl + (k + 2) * 128))[tc];
            float4 w3 = ((float4*)(Wl + (k + 3) * 128))[tc];
#pragma unroll
            for (int r = 0; r < 4; ++r) {
                float4 xv = *((float4*)(Xs + (tr * 4 + r) * 128 + k));
                acc[r][0] += xv.x * w0.x + xv.y * w1.x + xv.z * w2.x + xv.w * w3.x;
                acc[r][1] += xv.x * w0.y + xv.y * w1.y + xv.z * w2.y + xv.w * w3.y;
                acc[r][2] += xv.x * w0.z + xv.y * w1.z + xv.z * w2.z + xv.w * w3.z;
                acc[r][3] += xv.x * w0.w + xv.y * w1.w + xv.z * w2.w + xv.w * w3.w;
            }
        }
#pragma unroll
        for (int r = 0; r < 4; ++r) {
            int row = row0 + tr * 4 + r;
            if (row < nrows)
                ((float4*)(Y + (size_t)row * 128))[tc] =
                    make_float4(acc[r][0], acc[r][1], acc[r][2], acc[r][3]);
        }
    }
}

// ---------------- per-node attention logits (H=4, C=32) ----------------
__global__ void alpha_k(const float* __restrict__ Hm, const float* __restrict__ att_s,
                        const float* __restrict__ att_d,
                        float* __restrict__ asb, float* __restrict__ adb) {
    int n = blockIdx.x * 2 + (threadIdx.x >> 7);
    int c = threadIdx.x & 127;
    if (n >= NN) return;
    float v = Hm[(size_t)n * 128 + c];
    float ps = v * att_s[c];
    float pd = v * att_d[c];
    for (int off = 16; off > 0; off >>= 1) {
        ps += __shfl_down(ps, off, 32);
        pd += __shfl_down(pd, off, 32);
    }
    if ((threadIdx.x & 31) == 0) {
        int hd = c >> 5;
        asb[n * 4 + hd] = ps;
        adb[n * 4 + hd] = pd;
    }
}

// ---------------- fused softmax + aggregation + bias + ELU (H=4, C=32) ----------------
__global__ __launch_bounds__(256)
void agg_k(const float* __restrict__ Hm, const float* __restrict__ asb,
           const float* __restrict__ adb, const int* __restrict__ rp,
           const int* __restrict__ csr, const float* __restrict__ bias,
           float* __restrict__ Y) {
    int n = blockIdx.x * 4 + (threadIdx.x >> 6);
    if (n >= NN) return;
    int lane = threadIdx.x & 63;
    int hd0 = lane >> 5;       // head of channel `lane`
    int hd1 = hd0 + 2;         // head of channel `lane+64`
    float ad0 = adb[n * 4 + hd0];
    float ad1 = adb[n * 4 + hd1];
    float acc0 = 0.f, acc1 = 0.f, den0 = 0.f, den1 = 0.f;
    int e = rp[n], end = rp[n + 1];
    for (; e < end; ++e) {
        int s = csr[e];
        float e0 = __expf(leaky(asb[s * 4 + hd0] + ad0));
        float e1 = __expf(leaky(asb[s * 4 + hd1] + ad1));
        den0 += e0; den1 += e1;
        const float* hp = Hm + (size_t)s * 128;
        acc0 += e0 * hp[lane];
        acc1 += e1 * hp[lane + 64];
    }
    float o0 = acc0 / den0 + bias[lane];
    float o1 = acc1 / den1 + bias[lane + 64];
    Y[(size_t)n * 128 + lane]      = elu_f(o0);
    Y[(size_t)n * 128 + lane + 64] = elu_f(o1);
}

// ---------------- layer 3: [N,128]@[128,2] + logits ----------------
__global__ void l3pre_k(const float* __restrict__ Hm, const float* __restrict__ W3,
                        const float* __restrict__ atts, const float* __restrict__ attd,
                        float* __restrict__ h3, float* __restrict__ as3,
                        float* __restrict__ ad3) {
    int n = blockIdx.x * 4 + (threadIdx.x >> 6);
    if (n >= NN) return;
    int lane = threadIdx.x & 63;
    float x0 = Hm[(size_t)n * 128 + lane];
    float x1 = Hm[(size_t)n * 128 + lane + 64];
    float p0 = x0 * W3[lane * 2 + 0] + x1 * W3[(lane + 64) * 2 + 0];
    float p1 = x0 * W3[lane * 2 + 1] + x1 * W3[(lane + 64) * 2 + 1];
    for (int off = 32; off > 0; off >>= 1) {
        p0 += __shfl_down(p0, off, 64);
        p1 += __shfl_down(p1, off, 64);
    }
    if (lane == 0) {
        h3[n * 2 + 0] = p0;
        h3[n * 2 + 1] = p1;
        as3[n] = p0 * atts[0] + p1 * atts[1];
        ad3[n] = p0 * attd[0] + p1 * attd[1];
    }
}

__global__ void l3agg_k(const float* __restrict__ h3, const float* __restrict__ as3,
                        const float* __restrict__ ad3, const int* __restrict__ rp,
                        const int* __restrict__ csr, const float* __restrict__ b3,
                        float* __restrict__ out) {
    int n = blockIdx.x * blockDim.x + threadIdx.x;
    if (n >= NN) return;
    float adn = ad3[n];
    float den = 0.f, a0 = 0.f, a1 = 0.f;
    int end = rp[n + 1];
    for (int e = rp[n]; e < end; ++e) {
        int s = csr[e];
        float ev = __expf(leaky(as3[s] + adn));
        den += ev;
        a0 += ev * h3[s * 2 + 0];
        a1 += ev * h3[s * 2 + 1];
    }
    float o0 = a0 / den + b3[0];
    float o1 = a1 / den + b3[1];
    float m = fmaxf(o0, o1);
    float lse = m + logf(__expf(o0 - m) + __expf(o1 - m));
    out[n * 2 + 0] = o0 - lse;
    out[n * 2 + 1] = o1 - lse;
}

extern "C" void kernel_launch(void* const* d_in, const int* in_sizes, int n_in,
                              void* d_out, int out_size, void* d_ws, size_t ws_size,
                              hipStream_t stream) {
    const float* x   = (const float*)d_in[0];
    const int*   ei  = (const int*)d_in[1];
    const float* W1  = (const float*)d_in[2];
    const float* as1 = (const float*)d_in[3];
    const float* ad1 = (const float*)d_in[4];
    const float* b1  = (const float*)d_in[5];
    const float* W2  = (const float*)d_in[6];
    const float* as2 = (const float*)d_in[7];
    const float* ad2 = (const float*)d_in[8];
    const float* b2  = (const float*)d_in[9];
    const float* W3  = (const float*)d_in[10];
    const float* s3w = (const float*)d_in[11];
    const float* d3w = (const float*)d_in[12];
    const float* b3  = (const float*)d_in[13];
    float* out = (float*)d_out;

    char* ws = (char*)d_ws;
    size_t off = 0;
    auto alloc = [&](size_t bytes) -> char* {
        char* p = ws + off;
        off = (off + bytes + 255) & ~(size_t)255;
        return p;
    };
    float* hA     = (float*)alloc((size_t)NN * 128 * 4);
    float* hB     = (float*)alloc((size_t)NN * 128 * 4);
    float* asb    = (float*)alloc((size_t)NN * 4 * 4);
    float* adb    = (float*)alloc((size_t)NN * 4 * 4);
    int*   rp     = (int*)alloc((size_t)(NN + 1) * 4);
    int*   counts = (int*)alloc((size_t)NN * 4);
    int*   csr    = (int*)alloc((size_t)ET * 4);
    float* h3     = (float*)alloc((size_t)NN * 2 * 4);
    float* s3     = (float*)alloc((size_t)NN * 4);
    float* d3     = (float*)alloc((size_t)NN * 4);

    // CSR by destination (same for all 3 layers)
    hipMemsetAsync(counts, 0, (size_t)NN * 4, stream);
    hist_k<<<(ET + 255) / 256, 256, 0, stream>>>(ei, counts);
    scan_k<<<1, 256, 0, stream>>>(counts, rp);
    hipMemsetAsync(counts, 0, (size_t)NN * 4, stream);
    scatter_k<<<(ET + 255) / 256, 256, 0, stream>>>(ei, rp, counts, csr);

    // Layer 1
    gemm128_k<<<512, 256, 0, stream>>>(x, W1, hA, NN);
    alpha_k<<<NN / 2, 256, 0, stream>>>(hA, as1, ad1, asb, adb);
    agg_k<<<(NN + 3) / 4, 256, 0, stream>>>(hA, asb, adb, rp, csr, b1, hB);

    // Layer 2
    gemm128_k<<<512, 256, 0, stream>>>(hB, W2, hA, NN);
    alpha_k<<<NN / 2, 256, 0, stream>>>(hA, as2, ad2, asb, adb);
    agg_k<<<(NN + 3) / 4, 256, 0, stream>>>(hA, asb, adb, rp, csr, b2, hB);

    // Layer 3 + log_softmax
    l3pre_k<<<(NN + 3) / 4, 256, 0, stream>>>(hB, W3, s3w, d3w, h3, s3, d3);
    l3agg_k<<<(NN + 255) / 256, 256, 0, stream>>>(h3, s3, d3, rp, csr, b3, out);
}

// Round 2
// 505.795 us; speedup vs baseline: 1.3989x; 1.3989x over previous
//
#include <hip/hip_runtime.h>

#define NN 50000
#define EE 800000
#define ET 850000          // EE + NN self-loops
#define NEG 0.2f
#define SCAN_B 1024
#define NBLK ((NN + SCAN_B - 1) / SCAN_B)   // 49

__device__ __forceinline__ float leaky(float x) { return x > 0.f ? x : NEG * x; }
__device__ __forceinline__ float elu_f(float x) { return x > 0.f ? x : expm1f(x); }

// ---------------- CSR build (by destination) ----------------
__global__ void hist_k(const int* __restrict__ ei, int* __restrict__ counts) {
    int i = blockIdx.x * blockDim.x + threadIdx.x;
    if (i >= ET) return;
    int dst = (i < EE) ? ei[EE + i] : (i - EE);
    atomicAdd(&counts[dst], 1);
}

// two-level exclusive scan: scan1 (per-1024-block) -> scan2 (block sums) -> scan3 (add offsets)
__global__ void scan1_k(const int* __restrict__ counts, int* __restrict__ rp,
                        int* __restrict__ bsums) {
    __shared__ int lsum[256];
    int base = blockIdx.x * SCAN_B;
    int v[4];
    int tsum = 0;
#pragma unroll
    for (int j = 0; j < 4; ++j) {
        int i = base + threadIdx.x * 4 + j;
        v[j] = (i < NN) ? counts[i] : 0;
        tsum += v[j];
    }
    lsum[threadIdx.x] = tsum;
    __syncthreads();
    for (int off = 1; off < 256; off <<= 1) {
        int t = (threadIdx.x >= off) ? lsum[threadIdx.x - off] : 0;
        __syncthreads();
        lsum[threadIdx.x] += t;
        __syncthreads();
    }
    int excl = lsum[threadIdx.x] - tsum;   // exclusive over this block
#pragma unroll
    for (int j = 0; j < 4; ++j) {
        int i = base + threadIdx.x * 4 + j;
        if (i < NN) rp[i] = excl;
        excl += v[j];
    }
    if (threadIdx.x == 255) bsums[blockIdx.x] = lsum[255];
}

__global__ void scan2_k(int* __restrict__ bsums, int* __restrict__ rp) {
    int lane = threadIdx.x;               // single wave of 64
    int v = (lane < NBLK) ? bsums[lane] : 0;
    int orig = v;
    for (int off = 1; off < 64; off <<= 1) {
        int t = __shfl_up(v, off, 64);
        if (lane >= off) v += t;
    }
    if (lane < NBLK) bsums[lane] = v - orig;   // exclusive block offset
    if (lane == 63) rp[NN] = v;                // grand total
}

__global__ void scan3_k(int* __restrict__ rp, const int* __restrict__ bsums) {
    int add = bsums[blockIdx.x];
    int base = blockIdx.x * SCAN_B + threadIdx.x * 4;
#pragma unroll
    for (int j = 0; j < 4; ++j) {
        int i = base + j;
        if (i < NN) rp[i] += add;
    }
}

__global__ void scatter_k(const int* __restrict__ ei, const int* __restrict__ rp,
                          int* __restrict__ fill, int* __restrict__ csr) {
    int i = blockIdx.x * blockDim.x + threadIdx.x;
    if (i >= ET) return;
    int src, dst;
    if (i < EE) { src = ei[i]; dst = ei[EE + i]; }
    else        { src = dst = i - EE; }
    int pos = rp[dst] + atomicAdd(&fill[dst], 1);
    csr[pos] = src;
}

// ---------------- GEMM: [nrows,128] @ [128,128] ----------------
__global__ __launch_bounds__(256, 2)
void gemm128_k(const float* __restrict__ X, const float* __restrict__ W,
               float* __restrict__ Y, int nrows) {
    __shared__ __align__(16) float Wl[128 * 128];   // 64 KB
    __shared__ __align__(16) float Xs[32 * 128];    // 16 KB
    for (int i = threadIdx.x; i < 128 * 128 / 4; i += 256)
        ((float4*)Wl)[i] = ((const float4*)W)[i];

    int tc = threadIdx.x & 31;   // col group -> cols tc*4 .. tc*4+3
    int tr = threadIdx.x >> 5;   // row group -> rows tr*4 .. tr*4+3

    for (int row0 = blockIdx.x * 32; row0 < nrows; row0 += gridDim.x * 32) {
        __syncthreads();   // protect Xs (and initial Wl load)
        for (int i = threadIdx.x; i < 32 * 128 / 4; i += 256) {
            int r = i >> 5, c4 = i & 31;
            int row = row0 + r;
            float4 v = (row < nrows) ? ((const float4*)(X + (size_t)row * 128))[c4]
                                     : make_float4(0.f, 0.f, 0.f, 0.f);
            ((float4*)Xs)[i] = v;
        }
        __syncthreads();

        float acc[4][4] = {};
        for (int k = 0; k < 128; k += 4) {
            float4 w0 = ((float4*)(Wl + (k + 0) * 128))[tc];
            float4 w1 = ((float4*)(Wl + (k + 1) * 128))[tc];
            float4 w2 = ((float4*)(Wl + (k + 2) * 128))[tc];
            float4 w3 = ((float4*)(Wl + (k + 3) * 128))[tc];
#pragma unroll
            for (int r = 0; r < 4; ++r) {
                float4 xv = *((float4*)(Xs + (tr * 4 + r) * 128 + k));
                acc[r][0] += xv.x * w0.x + xv.y * w1.x + xv.z * w2.x + xv.w * w3.x;
                acc[r][1] += xv.x * w0.y + xv.y * w1.y + xv.z * w2.y + xv.w * w3.y;
                acc[r][2] += xv.x * w0.z + xv.y * w1.z + xv.z * w2.z + xv.w * w3.z;
                acc[r][3] += xv.x * w0.w + xv.y * w1.w + xv.z * w2.w + xv.w * w3.w;
            }
        }
#pragma unroll
        for (int r = 0; r < 4; ++r) {
            int row = row0 + tr * 4 + r;
            if (row < nrows)
                ((float4*)(Y + (size_t)row * 128))[tc] =
                    make_float4(acc[r][0], acc[r][1], acc[r][2], acc[r][3]);
        }
    }
}

// ---------------- per-node attention logits (H=4, C=32) ----------------
__global__ void alpha_k(const float* __restrict__ Hm, const float* __restrict__ att_s,
                        const float* __restrict__ att_d,
                        float* __restrict__ asb, float* __restrict__ adb) {
    int n = blockIdx.x * 2 + (threadIdx.x >> 7);
    int c = threadIdx.x & 127;
    if (n >= NN) return;
    float v = Hm[(size_t)n * 128 + c];
    float ps = v * att_s[c];
    float pd = v * att_d[c];
    for (int off = 16; off > 0; off >>= 1) {
        ps += __shfl_down(ps, off, 32);
        pd += __shfl_down(pd, off, 32);
    }
    if ((threadIdx.x & 31) == 0) {
        int hd = c >> 5;
        asb[n * 4 + hd] = ps;
        adb[n * 4 + hd] = pd;
    }
}

// ---------------- fused softmax + aggregation + bias + ELU (H=4, C=32) ----------------
__global__ __launch_bounds__(256)
void agg_k(const float* __restrict__ Hm, const float* __restrict__ asb,
           const float* __restrict__ adb, const int* __restrict__ rp,
           const int* __restrict__ csr, const float* __restrict__ bias,
           float* __restrict__ Y) {
    int n = blockIdx.x * 4 + (threadIdx.x >> 6);
    if (n >= NN) return;
    int lane = threadIdx.x & 63;
    int hd0 = lane >> 5;       // head of channel `lane`
    int hd1 = hd0 + 2;         // head of channel `lane+64`
    float ad0 = adb[n * 4 + hd0];
    float ad1 = adb[n * 4 + hd1];
    float acc0 = 0.f, acc1 = 0.f, den0 = 0.f, den1 = 0.f;
    int e = rp[n], end = rp[n + 1];
    for (; e < end; ++e) {
        int s = csr[e];
        float e0 = __expf(leaky(asb[s * 4 + hd0] + ad0));
        float e1 = __expf(leaky(asb[s * 4 + hd1] + ad1));
        den0 += e0; den1 += e1;
        const float* hp = Hm + (size_t)s * 128;
        acc0 += e0 * hp[lane];
        acc1 += e1 * hp[lane + 64];
    }
    float o0 = acc0 / den0 + bias[lane];
    float o1 = acc1 / den1 + bias[lane + 64];
    Y[(size_t)n * 128 + lane]      = elu_f(o0);
    Y[(size_t)n * 128 + lane + 64] = elu_f(o1);
}

// ---------------- layer 3: [N,128]@[128,2] + logits ----------------
__global__ void l3pre_k(const float* __restrict__ Hm, const float* __restrict__ W3,
                        const float* __restrict__ atts, const float* __restrict__ attd,
                        float* __restrict__ h3, float* __restrict__ as3,
                        float* __restrict__ ad3) {
    int n = blockIdx.x * 4 + (threadIdx.x >> 6);
    if (n >= NN) return;
    int lane = threadIdx.x & 63;
    float x0 = Hm[(size_t)n * 128 + lane];
    float x1 = Hm[(size_t)n * 128 + lane + 64];
    float p0 = x0 * W3[lane * 2 + 0] + x1 * W3[(lane + 64) * 2 + 0];
    float p1 = x0 * W3[lane * 2 + 1] + x1 * W3[(lane + 64) * 2 + 1];
    for (int off = 32; off > 0; off >>= 1) {
        p0 += __shfl_down(p0, off, 64);
        p1 += __shfl_down(p1, off, 64);
    }
    if (lane == 0) {
        h3[n * 2 + 0] = p0;
        h3[n * 2 + 1] = p1;
        as3[n] = p0 * atts[0] + p1 * atts[1];
        ad3[n] = p0 * attd[0] + p1 * attd[1];
    }
}

__global__ void l3agg_k(const float* __restrict__ h3, const float* __restrict__ as3,
                        const float* __restrict__ ad3, const int* __restrict__ rp,
                        const int* __restrict__ csr, const float* __restrict__ b3,
                        float* __restrict__ out) {
    int n = blockIdx.x * blockDim.x + threadIdx.x;
    if (n >= NN) return;
    float adn = ad3[n];
    float den = 0.f, a0 = 0.f, a1 = 0.f;
    int end = rp[n + 1];
    for (int e = rp[n]; e < end; ++e) {
        int s = csr[e];
        float ev = __expf(leaky(as3[s] + adn));
        den += ev;
        a0 += ev * h3[s * 2 + 0];
        a1 += ev * h3[s * 2 + 1];
    }
    float o0 = a0 / den + b3[0];
    float o1 = a1 / den + b3[1];
    float m = fmaxf(o0, o1);
    float lse = m + logf(__expf(o0 - m) + __expf(o1 - m));
    out[n * 2 + 0] = o0 - lse;
    out[n * 2 + 1] = o1 - lse;
}

extern "C" void kernel_launch(void* const* d_in, const int* in_sizes, int n_in,
                              void* d_out, int out_size, void* d_ws, size_t ws_size,
                              hipStream_t stream) {
    const float* x   = (const float*)d_in[0];
    const int*   ei  = (const int*)d_in[1];
    const float* W1  = (const float*)d_in[2];
    const float* as1 = (const float*)d_in[3];
    const float* ad1 = (const float*)d_in[4];
    const float* b1  = (const float*)d_in[5];
    const float* W2  = (const float*)d_in[6];
    const float* as2 = (const float*)d_in[7];
    const float* ad2 = (const float*)d_in[8];
    const float* b2  = (const float*)d_in[9];
    const float* W3  = (const float*)d_in[10];
    const float* s3w = (const float*)d_in[11];
    const float* d3w = (const float*)d_in[12];
    const float* b3  = (const float*)d_in[13];
    float* out = (float*)d_out;

    char* ws = (char*)d_ws;
    size_t off = 0;
    auto alloc = [&](size_t bytes) -> char* {
        char* p = ws + off;
        off = (off + bytes + 255) & ~(size_t)255;
        return p;
    };
    float* hA     = (float*)alloc((size_t)NN * 128 * 4);
    float* hB     = (float*)alloc((size_t)NN * 128 * 4);
    float* asb    = (float*)alloc((size_t)NN * 4 * 4);
    float* adb    = (float*)alloc((size_t)NN * 4 * 4);
    int*   rp     = (int*)alloc((size_t)(NN + 1) * 4);
    int*   counts = (int*)alloc((size_t)NN * 4);
    int*   csr    = (int*)alloc((size_t)ET * 4);
    int*   bsums  = (int*)alloc((size_t)NBLK * 4);
    float* h3     = (float*)alloc((size_t)NN * 2 * 4);
    float* s3     = (float*)alloc((size_t)NN * 4);
    float* d3     = (float*)alloc((size_t)NN * 4);

    // CSR by destination (same for all 3 layers)
    hipMemsetAsync(counts, 0, (size_t)NN * 4, stream);
    hist_k<<<(ET + 255) / 256, 256, 0, stream>>>(ei, counts);
    scan1_k<<<NBLK, 256, 0, stream>>>(counts, rp, bsums);
    scan2_k<<<1, 64, 0, stream>>>(bsums, rp);
    scan3_k<<<NBLK, 256, 0, stream>>>(rp, bsums);
    hipMemsetAsync(counts, 0, (size_t)NN * 4, stream);
    scatter_k<<<(ET + 255) / 256, 256, 0, stream>>>(ei, rp, counts, csr);

    // Layer 1
    gemm128_k<<<512, 256, 0, stream>>>(x, W1, hA, NN);
    alpha_k<<<NN / 2, 256, 0, stream>>>(hA, as1, ad1, asb, adb);
    agg_k<<<(NN + 3) / 4, 256, 0, stream>>>(hA, asb, adb, rp, csr, b1, hB);

    // Layer 2
    gemm128_k<<<512, 256, 0, stream>>>(hB, W2, hA, NN);
    alpha_k<<<NN / 2, 256, 0, stream>>>(hA, as2, ad2, asb, adb);
    agg_k<<<(NN + 3) / 4, 256, 0, stream>>>(hA, asb, adb, rp, csr, b2, hB);

    // Layer 3 + log_softmax
    l3pre_k<<<(NN + 3) / 4, 256, 0, stream>>>(hB, W3, s3w, d3w, h3, s3, d3);
    l3agg_k<<<(NN + 255) / 256, 256, 0, stream>>>(h3, s3, d3, rp, csr, b3, out);
}

// Round 3
// 399.148 us; speedup vs baseline: 1.7726x; 1.2672x over previous
//
#include <hip/hip_runtime.h>

#define NN 50000
#define EE 800000
#define ET 850000          // EE + NN self-loops
#define NEG 0.2f
#define SCAN_B 1024
#define NBLK ((NN + SCAN_B - 1) / SCAN_B)   // 49

__device__ __forceinline__ float leaky(float x) { return x > 0.f ? x : NEG * x; }
__device__ __forceinline__ float elu_f(float x) { return x > 0.f ? x : expm1f(x); }

// ---------------- CSR build (by destination) ----------------
__global__ void hist_k(const int* __restrict__ ei, int* __restrict__ counts) {
    int i = blockIdx.x * blockDim.x + threadIdx.x;
    if (i >= ET) return;
    int dst = (i < EE) ? ei[EE + i] : (i - EE);
    atomicAdd(&counts[dst], 1);
}

__global__ void scan1_k(const int* __restrict__ counts, int* __restrict__ rp,
                        int* __restrict__ bsums) {
    __shared__ int lsum[256];
    int base = blockIdx.x * SCAN_B;
    int v[4];
    int tsum = 0;
#pragma unroll
    for (int j = 0; j < 4; ++j) {
        int i = base + threadIdx.x * 4 + j;
        v[j] = (i < NN) ? counts[i] : 0;
        tsum += v[j];
    }
    lsum[threadIdx.x] = tsum;
    __syncthreads();
    for (int off = 1; off < 256; off <<= 1) {
        int t = (threadIdx.x >= off) ? lsum[threadIdx.x - off] : 0;
        __syncthreads();
        lsum[threadIdx.x] += t;
        __syncthreads();
    }
    int excl = lsum[threadIdx.x] - tsum;
#pragma unroll
    for (int j = 0; j < 4; ++j) {
        int i = base + threadIdx.x * 4 + j;
        if (i < NN) rp[i] = excl;
        excl += v[j];
    }
    if (threadIdx.x == 255) bsums[blockIdx.x] = lsum[255];
}

__global__ void scan2_k(int* __restrict__ bsums, int* __restrict__ rp) {
    int lane = threadIdx.x;
    int v = (lane < NBLK) ? bsums[lane] : 0;
    int orig = v;
    for (int off = 1; off < 64; off <<= 1) {
        int t = __shfl_up(v, off, 64);
        if (lane >= off) v += t;
    }
    if (lane < NBLK) bsums[lane] = v - orig;
    if (lane == 63) rp[NN] = v;
}

__global__ void scan3_k(int* __restrict__ rp, const int* __restrict__ bsums) {
    int add = bsums[blockIdx.x];
    int base = blockIdx.x * SCAN_B + threadIdx.x * 4;
#pragma unroll
    for (int j = 0; j < 4; ++j) {
        int i = base + j;
        if (i < NN) rp[i] += add;
    }
}

__global__ void scatter_k(const int* __restrict__ ei, const int* __restrict__ rp,
                          int* __restrict__ fill, int* __restrict__ csr) {
    int i = blockIdx.x * blockDim.x + threadIdx.x;
    if (i >= ET) return;
    int src, dst;
    if (i < EE) { src = ei[i]; dst = ei[EE + i]; }
    else        { src = dst = i - EE; }
    int pos = rp[dst] + atomicAdd(&fill[dst], 1);
    csr[pos] = src;
}

// ---- GEMM [nrows,128]@[128,128] with fused per-node attention logits ----
__global__ __launch_bounds__(256, 2)
void gemm128_k(const float* __restrict__ X, const float* __restrict__ W,
               float* __restrict__ Y, int nrows,
               const float* __restrict__ att_s, const float* __restrict__ att_d,
               float* __restrict__ asb, float* __restrict__ adb) {
    __shared__ __align__(16) float Wl[128 * 128];   // 64 KB
    __shared__ __align__(16) float Xs[32 * 128];    // 16 KB (reused as reduce scratch)
    for (int i = threadIdx.x; i < 128 * 128 / 4; i += 256)
        ((float4*)Wl)[i] = ((const float4*)W)[i];

    int tc = threadIdx.x & 31;   // cols tc*4 .. tc*4+3
    int tr = threadIdx.x >> 5;   // rows tr*4 .. tr*4+3
    float4 avs = ((const float4*)att_s)[tc];
    float4 avd = ((const float4*)att_d)[tc];

    for (int row0 = blockIdx.x * 32; row0 < nrows; row0 += gridDim.x * 32) {
        __syncthreads();   // protect Xs (compute + reduce of previous tile done)
        for (int i = threadIdx.x; i < 32 * 128 / 4; i += 256) {
            int r = i >> 5, c4 = i & 31;
            int row = row0 + r;
            float4 v = (row < nrows) ? ((const float4*)(X + (size_t)row * 128))[c4]
                                     : make_float4(0.f, 0.f, 0.f, 0.f);
            ((float4*)Xs)[i] = v;
        }
        __syncthreads();

        float acc[4][4] = {};
        for (int k = 0; k < 128; k += 4) {
            float4 w0 = ((float4*)(Wl + (k + 0) * 128))[tc];
            float4 w1 = ((float4*)(Wl + (k + 1) * 128))[tc];
            float4 w2 = ((float4*)(Wl + (k + 2) * 128))[tc];
            float4 w3 = ((float4*)(Wl + (k + 3) * 128))[tc];
#pragma unroll
            for (int r = 0; r < 4; ++r) {
                float4 xv = *((float4*)(Xs + (tr * 4 + r) * 128 + k));
                acc[r][0] += xv.x * w0.x + xv.y * w1.x + xv.z * w2.x + xv.w * w3.x;
                acc[r][1] += xv.x * w0.y + xv.y * w1.y + xv.z * w2.y + xv.w * w3.y;
                acc[r][2] += xv.x * w0.z + xv.y * w1.z + xv.z * w2.z + xv.w * w3.z;
                acc[r][3] += xv.x * w0.w + xv.y * w1.w + xv.z * w2.w + xv.w * w3.w;
            }
        }
#pragma unroll
        for (int r = 0; r < 4; ++r) {
            int row = row0 + tr * 4 + r;
            if (row < nrows)
                ((float4*)(Y + (size_t)row * 128))[tc] =
                    make_float4(acc[r][0], acc[r][1], acc[r][2], acc[r][3]);
        }

        // fused alpha: per-row per-head dot with att_src/att_dst
        __syncthreads();               // done reading Xs for compute
        float* red = Xs;               // [2][32][33] padded
#pragma unroll
        for (int r = 0; r < 4; ++r) {
            int rl = tr * 4 + r;
            float ps = acc[r][0]*avs.x + acc[r][1]*avs.y + acc[r][2]*avs.z + acc[r][3]*avs.w;
            float pd = acc[r][0]*avd.x + acc[r][1]*avd.y + acc[r][2]*avd.z + acc[r][3]*avd.w;
            red[(0*32 + rl)*33 + tc] = ps;
            red[(1*32 + rl)*33 + tc] = pd;
        }
        __syncthreads();
        {
            int rl = threadIdx.x & 31;
            int j  = threadIdx.x >> 5;     // 0..7 -> (head, s/d)
            int head = j >> 1, sd = j & 1;
            float sum = 0.f;
#pragma unroll
            for (int q = 0; q < 8; ++q)
                sum += red[(sd*32 + rl)*33 + head*8 + q];
            int row = row0 + rl;
            if (row < nrows) (sd ? adb : asb)[row*4 + head] = sum;
        }
    }
}

// ---- fused softmax + aggregation + bias + ELU (+ optional layer-3 projection) ----
__global__ __launch_bounds__(256)
void agg_k(const float* __restrict__ Hm, const float* __restrict__ asb,
           const float* __restrict__ adb, const int* __restrict__ rp,
           const int* __restrict__ csr, const float* __restrict__ bias,
           float* __restrict__ Y,
           const float* __restrict__ W3, const float* __restrict__ s3w,
           const float* __restrict__ d3w, float* __restrict__ h3,
           float* __restrict__ as3, float* __restrict__ ad3) {
    int n = blockIdx.x * 4 + (threadIdx.x >> 6);
    if (n >= NN) return;
    int lane = threadIdx.x & 63;          // owns channels 2*lane, 2*lane+1
    int hd = lane >> 4;                   // head of this channel pair
    const float2* H2 = (const float2*)Hm;
    float ad = adb[n * 4 + hd];
    float accx = 0.f, accy = 0.f, den = 0.f;
    int e = rp[n], end = rp[n + 1];
    int last = end - 1;
    for (int base = e; base < end; base += 8) {
        int s[8]; float a[8]; float2 h[8];
#pragma unroll
        for (int j = 0; j < 8; ++j) {
            int i = base + j;
            s[j] = csr[i <= last ? i : last];
        }
#pragma unroll
        for (int j = 0; j < 8; ++j) a[j] = asb[s[j] * 4 + hd] + ad;
#pragma unroll
        for (int j = 0; j < 8; ++j) h[j] = H2[(size_t)s[j] * 64 + lane];
#pragma unroll
        for (int j = 0; j < 8; ++j) {
            float w = __expf(leaky(a[j]));
            w = (base + j <= last) ? w : 0.f;   // mask duplicated tail edges
            den += w;
            accx += w * h[j].x;
            accy += w * h[j].y;
        }
    }
    float2 bv = ((const float2*)bias)[lane];
    float ox = elu_f(accx / den + bv.x);
    float oy = elu_f(accy / den + bv.y);
    if (!W3) {
        ((float2*)(Y + (size_t)n * 128))[lane] = make_float2(ox, oy);
    } else {
        // fused layer-3 projection: p = o @ W3  (128 -> 2), per-wave reduce
        float4 q = ((const float4*)W3)[lane];   // {w(c,0), w(c,1), w(c+1,0), w(c+1,1)}
        float p0 = ox * q.x + oy * q.z;
        float p1 = ox * q.y + oy * q.w;
        for (int off = 32; off > 0; off >>= 1) {
            p0 += __shfl_down(p0, off, 64);
            p1 += __shfl_down(p1, off, 64);
        }
        if (lane == 0) {
            h3[n * 2 + 0] = p0;
            h3[n * 2 + 1] = p1;
            as3[n] = p0 * s3w[0] + p1 * s3w[1];
            ad3[n] = p0 * d3w[0] + p1 * d3w[1];
        }
    }
}

// ---- layer-3 aggregation + log_softmax ----
__global__ void l3agg_k(const float* __restrict__ h3, const float* __restrict__ as3,
                        const float* __restrict__ ad3, const int* __restrict__ rp,
                        const int* __restrict__ csr, const float* __restrict__ b3,
                        float* __restrict__ out) {
    int n = blockIdx.x * blockDim.x + threadIdx.x;
    if (n >= NN) return;
    const float2* h2 = (const float2*)h3;
    float adn = ad3[n];
    float den = 0.f, a0 = 0.f, a1 = 0.f;
    int e = rp[n], end = rp[n + 1], last = end - 1;
    for (int base = e; base < end; base += 4) {
        int s[4]; float al[4]; float2 g[4];
#pragma unroll
        for (int j = 0; j < 4; ++j) {
            int i = base + j;
            s[j] = csr[i <= last ? i : last];
        }
#pragma unroll
        for (int j = 0; j < 4; ++j) al[j] = as3[s[j]] + adn;
#pragma unroll
        for (int j = 0; j < 4; ++j) g[j] = h2[s[j]];
#pragma unroll
        for (int j = 0; j < 4; ++j) {
            float w = __expf(leaky(al[j]));
            w = (base + j <= last) ? w : 0.f;
            den += w;
            a0 += w * g[j].x;
            a1 += w * g[j].y;
        }
    }
    float o0 = a0 / den + b3[0];
    float o1 = a1 / den + b3[1];
    float m = fmaxf(o0, o1);
    float lse = m + logf(__expf(o0 - m) + __expf(o1 - m));
    out[n * 2 + 0] = o0 - lse;
    out[n * 2 + 1] = o1 - lse;
}

extern "C" void kernel_launch(void* const* d_in, const int* in_sizes, int n_in,
                              void* d_out, int out_size, void* d_ws, size_t ws_size,
                              hipStream_t stream) {
    const float* x   = (const float*)d_in[0];
    const int*   ei  = (const int*)d_in[1];
    const float* W1  = (const float*)d_in[2];
    const float* as1 = (const float*)d_in[3];
    const float* ad1 = (const float*)d_in[4];
    const float* b1  = (const float*)d_in[5];
    const float* W2  = (const float*)d_in[6];
    const float* as2 = (const float*)d_in[7];
    const float* ad2 = (const float*)d_in[8];
    const float* b2  = (const float*)d_in[9];
    const float* W3  = (const float*)d_in[10];
    const float* s3w = (const float*)d_in[11];
    const float* d3w = (const float*)d_in[12];
    const float* b3  = (const float*)d_in[13];
    float* out = (float*)d_out;

    char* ws = (char*)d_ws;
    size_t off = 0;
    auto alloc = [&](size_t bytes) -> char* {
        char* p = ws + off;
        off = (off + bytes + 255) & ~(size_t)255;
        return p;
    };
    float* hA     = (float*)alloc((size_t)NN * 128 * 4);
    float* hB     = (float*)alloc((size_t)NN * 128 * 4);
    float* asb    = (float*)alloc((size_t)NN * 4 * 4);
    float* adb    = (float*)alloc((size_t)NN * 4 * 4);
    int*   rp     = (int*)alloc((size_t)(NN + 1) * 4);
    int*   counts = (int*)alloc((size_t)NN * 4);
    int*   csr    = (int*)alloc((size_t)ET * 4);
    int*   bsums  = (int*)alloc((size_t)NBLK * 4);
    float* h3     = (float*)alloc((size_t)NN * 2 * 4);
    float* s3     = (float*)alloc((size_t)NN * 4);
    float* d3     = (float*)alloc((size_t)NN * 4);

    // CSR by destination (shared by all 3 layers)
    hipMemsetAsync(counts, 0, (size_t)NN * 4, stream);
    hist_k<<<(ET + 255) / 256, 256, 0, stream>>>(ei, counts);
    scan1_k<<<NBLK, 256, 0, stream>>>(counts, rp, bsums);
    scan2_k<<<1, 64, 0, stream>>>(bsums, rp);
    scan3_k<<<NBLK, 256, 0, stream>>>(rp, bsums);
    hipMemsetAsync(counts, 0, (size_t)NN * 4, stream);
    scatter_k<<<(ET + 255) / 256, 256, 0, stream>>>(ei, rp, counts, csr);

    // Layer 1 (alpha fused into gemm epilogue)
    gemm128_k<<<512, 256, 0, stream>>>(x, W1, hA, NN, as1, ad1, asb, adb);
    agg_k<<<(NN + 3) / 4, 256, 0, stream>>>(hA, asb, adb, rp, csr, b1, hB,
                                            nullptr, nullptr, nullptr,
                                            nullptr, nullptr, nullptr);

    // Layer 2 (+ fused layer-3 projection/logits in agg epilogue)
    gemm128_k<<<512, 256, 0, stream>>>(hB, W2, hA, NN, as2, ad2, asb, adb);
    agg_k<<<(NN + 3) / 4, 256, 0, stream>>>(hA, asb, adb, rp, csr, b2, nullptr,
                                            W3, s3w, d3w, h3, s3, d3);

    // Layer 3 aggregation + log_softmax
    l3agg_k<<<(NN + 255) / 256, 256, 0, stream>>>(h3, s3, d3, rp, csr, b3, out);
}

// Round 4
// 332.900 us; speedup vs baseline: 2.1254x; 1.1990x over previous
//
#include <hip/hip_runtime.h>
#include <hip/hip_fp16.h>

#define NN 50000
#define EE 800000
#define ET 850000          // EE + NN self-loops
#define NEG 0.2f
#define SCAN_B 1024
#define NBLK ((NN + SCAN_B - 1) / SCAN_B)   // 49

__device__ __forceinline__ float leaky(float x) { return fmaxf(x, NEG * x); }
__device__ __forceinline__ float elu_f(float x) { return x > 0.f ? x : expm1f(x); }

struct alignas(8) half4 { __half2 a, b; };

// ---------------- CSR build (by destination) ----------------
__global__ void hist_k(const int* __restrict__ ei, int* __restrict__ counts) {
    int i = blockIdx.x * blockDim.x + threadIdx.x;
    if (i >= ET) return;
    int dst = (i < EE) ? ei[EE + i] : (i - EE);
    atomicAdd(&counts[dst], 1);
}

__global__ void scan1_k(const int* __restrict__ counts, int* __restrict__ rp,
                        int* __restrict__ bsums) {
    __shared__ int lsum[256];
    int base = blockIdx.x * SCAN_B;
    int v[4];
    int tsum = 0;
#pragma unroll
    for (int j = 0; j < 4; ++j) {
        int i = base + threadIdx.x * 4 + j;
        v[j] = (i < NN) ? counts[i] : 0;
        tsum += v[j];
    }
    lsum[threadIdx.x] = tsum;
    __syncthreads();
    for (int off = 1; off < 256; off <<= 1) {
        int t = (threadIdx.x >= off) ? lsum[threadIdx.x - off] : 0;
        __syncthreads();
        lsum[threadIdx.x] += t;
        __syncthreads();
    }
    int excl = lsum[threadIdx.x] - tsum;
#pragma unroll
    for (int j = 0; j < 4; ++j) {
        int i = base + threadIdx.x * 4 + j;
        if (i < NN) rp[i] = excl;
        excl += v[j];
    }
    if (threadIdx.x == 255) bsums[blockIdx.x] = lsum[255];
}

__global__ void scan2_k(int* __restrict__ bsums, int* __restrict__ rp) {
    int lane = threadIdx.x;
    int v = (lane < NBLK) ? bsums[lane] : 0;
    int orig = v;
    for (int off = 1; off < 64; off <<= 1) {
        int t = __shfl_up(v, off, 64);
        if (lane >= off) v += t;
    }
    if (lane < NBLK) bsums[lane] = v - orig;
    if (lane == 63) rp[NN] = v;
}

__global__ void scan3_k(int* __restrict__ rp, const int* __restrict__ bsums) {
    int add = bsums[blockIdx.x];
    int base = blockIdx.x * SCAN_B + threadIdx.x * 4;
#pragma unroll
    for (int j = 0; j < 4; ++j) {
        int i = base + j;
        if (i < NN) rp[i] += add;
    }
}

__global__ void scatter_k(const int* __restrict__ ei, const int* __restrict__ rp,
                          int* __restrict__ fill, int* __restrict__ csr) {
    int i = blockIdx.x * blockDim.x + threadIdx.x;
    if (i >= ET) return;
    int src, dst;
    if (i < EE) { src = ei[i]; dst = ei[EE + i]; }
    else        { src = dst = i - EE; }
    int pos = rp[dst] + atomicAdd(&fill[dst], 1);
    csr[pos] = src;
}

// ---- GEMM [nrows,128]@[128,128], fp16 output + fused attention logits ----
__global__ __launch_bounds__(256, 2)
void gemm128_k(const float* __restrict__ X, const float* __restrict__ W,
               __half* __restrict__ Yh, int nrows,
               const float* __restrict__ att_s, const float* __restrict__ att_d,
               float* __restrict__ asb, float* __restrict__ adb) {
    __shared__ __align__(16) float Wl[128 * 128];   // 64 KB
    __shared__ __align__(16) float Xs[32 * 128];    // 16 KB (reused as reduce scratch)
    for (int i = threadIdx.x; i < 128 * 128 / 4; i += 256)
        ((float4*)Wl)[i] = ((const float4*)W)[i];

    int tc = threadIdx.x & 31;   // cols tc*4 .. tc*4+3
    int tr = threadIdx.x >> 5;   // rows tr*4 .. tr*4+3
    float4 avs = ((const float4*)att_s)[tc];
    float4 avd = ((const float4*)att_d)[tc];

    for (int row0 = blockIdx.x * 32; row0 < nrows; row0 += gridDim.x * 32) {
        __syncthreads();
        for (int i = threadIdx.x; i < 32 * 128 / 4; i += 256) {
            int r = i >> 5, c4 = i & 31;
            int row = row0 + r;
            float4 v = (row < nrows) ? ((const float4*)(X + (size_t)row * 128))[c4]
                                     : make_float4(0.f, 0.f, 0.f, 0.f);
            ((float4*)Xs)[i] = v;
        }
        __syncthreads();

        float acc[4][4] = {};
        for (int k = 0; k < 128; k += 4) {
            float4 w0 = ((float4*)(Wl + (k + 0) * 128))[tc];
            float4 w1 = ((float4*)(Wl + (k + 1) * 128))[tc];
            float4 w2 = ((float4*)(Wl + (k + 2) * 128))[tc];
            float4 w3 = ((float4*)(Wl + (k + 3) * 128))[tc];
#pragma unroll
            for (int r = 0; r < 4; ++r) {
                float4 xv = *((float4*)(Xs + (tr * 4 + r) * 128 + k));
                acc[r][0] += xv.x * w0.x + xv.y * w1.x + xv.z * w2.x + xv.w * w3.x;
                acc[r][1] += xv.x * w0.y + xv.y * w1.y + xv.z * w2.y + xv.w * w3.y;
                acc[r][2] += xv.x * w0.z + xv.y * w1.z + xv.z * w2.z + xv.w * w3.z;
                acc[r][3] += xv.x * w0.w + xv.y * w1.w + xv.z * w2.w + xv.w * w3.w;
            }
        }
#pragma unroll
        for (int r = 0; r < 4; ++r) {
            int row = row0 + tr * 4 + r;
            if (row < nrows) {
                half4 hv;
                hv.a = __floats2half2_rn(acc[r][0], acc[r][1]);
                hv.b = __floats2half2_rn(acc[r][2], acc[r][3]);
                ((half4*)(Yh + (size_t)row * 128))[tc] = hv;
            }
        }

        // fused alpha: per-row per-head dot with att_src/att_dst
        __syncthreads();
        float* red = Xs;               // [2][32][33] padded
#pragma unroll
        for (int r = 0; r < 4; ++r) {
            int rl = tr * 4 + r;
            float ps = acc[r][0]*avs.x + acc[r][1]*avs.y + acc[r][2]*avs.z + acc[r][3]*avs.w;
            float pd = acc[r][0]*avd.x + acc[r][1]*avd.y + acc[r][2]*avd.z + acc[r][3]*avd.w;
            red[(0*32 + rl)*33 + tc] = ps;
            red[(1*32 + rl)*33 + tc] = pd;
        }
        __syncthreads();
        {
            int rl = threadIdx.x & 31;
            int j  = threadIdx.x >> 5;     // 0..7 -> (head, s/d)
            int head = j >> 1, sd = j & 1;
            float sum = 0.f;
#pragma unroll
            for (int q = 0; q < 8; ++q)
                sum += red[(sd*32 + rl)*33 + head*8 + q];
            int row = row0 + rl;
            if (row < nrows) (sd ? adb : asb)[row*4 + head] = sum;
        }
    }
}

// ---- fused softmax + aggregation + bias + ELU (+ optional layer-3 projection) ----
// 2 nodes per wave: half-wave (32 lanes) per node, 4 channels per lane (half4 row load)
__global__ __launch_bounds__(256)
void agg_k(const __half* __restrict__ Hh, const float* __restrict__ asb,
           const float* __restrict__ adb, const int* __restrict__ rp,
           const int* __restrict__ csr, const float* __restrict__ bias,
           float* __restrict__ Y,
           const float* __restrict__ W3, const float* __restrict__ s3w,
           const float* __restrict__ d3w, float* __restrict__ h3,
           float* __restrict__ as3, float* __restrict__ ad3) {
    int lane = threadIdx.x & 63;
    int hw = lane >> 5;                   // half-wave id
    int l  = lane & 31;                   // owns channels l*4 .. l*4+3
    int n = blockIdx.x * 8 + (threadIdx.x >> 6) * 2 + hw;
    if (n >= NN) return;
    int hd = l >> 3;                      // head of this channel quad
    float ad = adb[n * 4 + hd];
    float acc0 = 0.f, acc1 = 0.f, acc2 = 0.f, acc3 = 0.f, den = 0.f;
    int e = rp[n], end = rp[n + 1], last = end - 1;
    for (int base = e; base < end; base += 8) {
        int s[8]; float a[8]; float2 hraw[8];
#pragma unroll
        for (int j = 0; j < 8; ++j) {
            int i = base + j;
            s[j] = csr[i <= last ? i : last];
        }
#pragma unroll
        for (int j = 0; j < 8; ++j) a[j] = asb[s[j] * 4 + hd] + ad;
#pragma unroll
        for (int j = 0; j < 8; ++j)
            hraw[j] = ((const float2*)(Hh + (size_t)s[j] * 128))[l];
#pragma unroll
        for (int j = 0; j < 8; ++j) {
            float w = __expf(leaky(a[j]));
            w = (base + j <= last) ? w : 0.f;   // mask duplicated tail edges
            den += w;
            const __half2* hp = (const __half2*)&hraw[j];
            float2 f01 = __half22float2(hp[0]);
            float2 f23 = __half22float2(hp[1]);
            acc0 += w * f01.x; acc1 += w * f01.y;
            acc2 += w * f23.x; acc3 += w * f23.y;
        }
    }
    float4 bv = ((const float4*)bias)[l];
    float inv = 1.f / den;
    float o0 = elu_f(acc0 * inv + bv.x);
    float o1 = elu_f(acc1 * inv + bv.y);
    float o2 = elu_f(acc2 * inv + bv.z);
    float o3 = elu_f(acc3 * inv + bv.w);
    if (!W3) {
        ((float4*)(Y + (size_t)n * 128))[l] = make_float4(o0, o1, o2, o3);
    } else {
        // fused layer-3 projection: p = o @ W3  (128 -> 2), half-wave reduce
        float4 wa = ((const float4*)W3)[l * 2];     // rows c0,c1
        float4 wb = ((const float4*)W3)[l * 2 + 1]; // rows c2,c3
        float p0 = o0 * wa.x + o1 * wa.z + o2 * wb.x + o3 * wb.z;
        float p1 = o0 * wa.y + o1 * wa.w + o2 * wb.y + o3 * wb.w;
        for (int off = 16; off > 0; off >>= 1) {
            p0 += __shfl_down(p0, off, 32);
            p1 += __shfl_down(p1, off, 32);
        }
        if (l == 0) {
            h3[n * 2 + 0] = p0;
            h3[n * 2 + 1] = p1;
            as3[n] = p0 * s3w[0] + p1 * s3w[1];
            ad3[n] = p0 * d3w[0] + p1 * d3w[1];
        }
    }
}

// ---- layer-3 aggregation + log_softmax ----
__global__ void l3agg_k(const float* __restrict__ h3, const float* __restrict__ as3,
                        const float* __restrict__ ad3, const int* __restrict__ rp,
                        const int* __restrict__ csr, const float* __restrict__ b3,
                        float* __restrict__ out) {
    int n = blockIdx.x * blockDim.x + threadIdx.x;
    if (n >= NN) return;
    const float2* h2 = (const float2*)h3;
    float adn = ad3[n];
    float den = 0.f, a0 = 0.f, a1 = 0.f;
    int e = rp[n], end = rp[n + 1], last = end - 1;
    for (int base = e; base < end; base += 4) {
        int s[4]; float al[4]; float2 g[4];
#pragma unroll
        for (int j = 0; j < 4; ++j) {
            int i = base + j;
            s[j] = csr[i <= last ? i : last];
        }
#pragma unroll
        for (int j = 0; j < 4; ++j) al[j] = as3[s[j]] + adn;
#pragma unroll
        for (int j = 0; j < 4; ++j) g[j] = h2[s[j]];
#pragma unroll
        for (int j = 0; j < 4; ++j) {
            float w = __expf(leaky(al[j]));
            w = (base + j <= last) ? w : 0.f;
            den += w;
            a0 += w * g[j].x;
            a1 += w * g[j].y;
        }
    }
    float o0 = a0 / den + b3[0];
    float o1 = a1 / den + b3[1];
    float m = fmaxf(o0, o1);
    float lse = m + logf(__expf(o0 - m) + __expf(o1 - m));
    out[n * 2 + 0] = o0 - lse;
    out[n * 2 + 1] = o1 - lse;
}

extern "C" void kernel_launch(void* const* d_in, const int* in_sizes, int n_in,
                              void* d_out, int out_size, void* d_ws, size_t ws_size,
                              hipStream_t stream) {
    const float* x   = (const float*)d_in[0];
    const int*   ei  = (const int*)d_in[1];
    const float* W1  = (const float*)d_in[2];
    const float* as1 = (const float*)d_in[3];
    const float* ad1 = (const float*)d_in[4];
    const float* b1  = (const float*)d_in[5];
    const float* W2  = (const float*)d_in[6];
    const float* as2 = (const float*)d_in[7];
    const float* ad2 = (const float*)d_in[8];
    const float* b2  = (const float*)d_in[9];
    const float* W3  = (const float*)d_in[10];
    const float* s3w = (const float*)d_in[11];
    const float* d3w = (const float*)d_in[12];
    const float* b3  = (const float*)d_in[13];
    float* out = (float*)d_out;

    char* ws = (char*)d_ws;
    size_t off = 0;
    auto alloc = [&](size_t bytes) -> char* {
        char* p = ws + off;
        off = (off + bytes + 255) & ~(size_t)255;
        return p;
    };
    __half* hA    = (__half*)alloc((size_t)NN * 128 * 2);   // fp16 gather table
    float* hB     = (float*)alloc((size_t)NN * 128 * 4);    // agg1 out (gemm2 in)
    float* asb    = (float*)alloc((size_t)NN * 4 * 4);
    float* adb    = (float*)alloc((size_t)NN * 4 * 4);
    int*   rp     = (int*)alloc((size_t)(NN + 1) * 4);
    int*   counts = (int*)alloc((size_t)NN * 4);
    int*   csr    = (int*)alloc((size_t)ET * 4);
    int*   bsums  = (int*)alloc((size_t)NBLK * 4);
    float* h3     = (float*)alloc((size_t)NN * 2 * 4);
    float* s3     = (float*)alloc((size_t)NN * 4);
    float* d3     = (float*)alloc((size_t)NN * 4);

    // CSR by destination (shared by all 3 layers)
    hipMemsetAsync(counts, 0, (size_t)NN * 4, stream);
    hist_k<<<(ET + 255) / 256, 256, 0, stream>>>(ei, counts);
    scan1_k<<<NBLK, 256, 0, stream>>>(counts, rp, bsums);
    scan2_k<<<1, 64, 0, stream>>>(bsums, rp);
    scan3_k<<<NBLK, 256, 0, stream>>>(rp, bsums);
    hipMemsetAsync(counts, 0, (size_t)NN * 4, stream);
    scatter_k<<<(ET + 255) / 256, 256, 0, stream>>>(ei, rp, counts, csr);

    // Layer 1 (alpha fused into gemm epilogue)
    gemm128_k<<<512, 256, 0, stream>>>(x, W1, hA, NN, as1, ad1, asb, adb);
    agg_k<<<(NN + 7) / 8, 256, 0, stream>>>(hA, asb, adb, rp, csr, b1, hB,
                                            nullptr, nullptr, nullptr,
                                            nullptr, nullptr, nullptr);

    // Layer 2 (+ fused layer-3 projection/logits in agg epilogue)
    gemm128_k<<<512, 256, 0, stream>>>(hB, W2, hA, NN, as2, ad2, asb, adb);
    agg_k<<<(NN + 7) / 8, 256, 0, stream>>>(hA, asb, adb, rp, csr, b2, nullptr,
                                            W3, s3w, d3w, h3, s3, d3);

    // Layer 3 aggregation + log_softmax
    l3agg_k<<<(NN + 255) / 256, 256, 0, stream>>>(h3, s3, d3, rp, csr, b3, out);
}

// Round 5
// 290.646 us; speedup vs baseline: 2.4344x; 1.1454x over previous
//
#include <hip/hip_runtime.h>
#include <hip/hip_fp16.h>

#define NN 50000
#define EE 800000
#define ET 850000          // EE + NN self-loops
#define NEG 0.2f
#define SCAN_B 1024
#define NBLK ((NN + SCAN_B - 1) / SCAN_B)   // 49

__device__ __forceinline__ float leaky(float x) { return fmaxf(x, NEG * x); }
__device__ __forceinline__ float elu_f(float x) { return x > 0.f ? x : expm1f(x); }

struct alignas(8) half4 { __half2 a, b; };

typedef _Float16 half8_t __attribute__((ext_vector_type(8)));
typedef float float4_t __attribute__((ext_vector_type(4)));

// ---------------- CSR build (by destination) ----------------
// hist also records each edge's arrival rank -> scatter needs no atomic
__global__ void hist_k(const int* __restrict__ ei, int* __restrict__ counts,
                       int* __restrict__ rank) {
    int i = blockIdx.x * blockDim.x + threadIdx.x;
    if (i >= ET) return;
    int dst = (i < EE) ? ei[EE + i] : (i - EE);
    rank[i] = atomicAdd(&counts[dst], 1);
}

__global__ void scan1_k(const int* __restrict__ counts, int* __restrict__ rp,
                        int* __restrict__ bsums) {
    __shared__ int lsum[256];
    int base = blockIdx.x * SCAN_B;
    int v[4];
    int tsum = 0;
#pragma unroll
    for (int j = 0; j < 4; ++j) {
        int i = base + threadIdx.x * 4 + j;
        v[j] = (i < NN) ? counts[i] : 0;
        tsum += v[j];
    }
    lsum[threadIdx.x] = tsum;
    __syncthreads();
    for (int off = 1; off < 256; off <<= 1) {
        int t = (threadIdx.x >= off) ? lsum[threadIdx.x - off] : 0;
        __syncthreads();
        lsum[threadIdx.x] += t;
        __syncthreads();
    }
    int excl = lsum[threadIdx.x] - tsum;
#pragma unroll
    for (int j = 0; j < 4; ++j) {
        int i = base + threadIdx.x * 4 + j;
        if (i < NN) rp[i] = excl;
        excl += v[j];
    }
    if (threadIdx.x == 255) bsums[blockIdx.x] = lsum[255];
}

__global__ void scan2_k(int* __restrict__ bsums, int* __restrict__ rp) {
    int lane = threadIdx.x;
    int v = (lane < NBLK) ? bsums[lane] : 0;
    int orig = v;
    for (int off = 1; off < 64; off <<= 1) {
        int t = __shfl_up(v, off, 64);
        if (lane >= off) v += t;
    }
    if (lane < NBLK) bsums[lane] = v - orig;
    if (lane == 63) rp[NN] = v;
}

__global__ void scan3_k(int* __restrict__ rp, const int* __restrict__ bsums) {
    int add = bsums[blockIdx.x];
    int base = blockIdx.x * SCAN_B + threadIdx.x * 4;
#pragma unroll
    for (int j = 0; j < 4; ++j) {
        int i = base + j;
        if (i < NN) rp[i] += add;
    }
}

__global__ void scatter_k(const int* __restrict__ ei, const int* __restrict__ rp,
                          const int* __restrict__ rank, int* __restrict__ csr) {
    int i = blockIdx.x * blockDim.x + threadIdx.x;
    if (i >= ET) return;
    int src, dst;
    if (i < EE) { src = ei[i]; dst = ei[EE + i]; }
    else        { src = dst = i - EE; }
    csr[rp[dst] + rank[i]] = src;
}

// ---- transpose W (fp32 [128][128] k-major) -> Wt (fp16 [128][128] n-major) ----
__global__ void wt_k(const float* __restrict__ W, __half* __restrict__ Wt) {
    int i = blockIdx.x * 256 + threadIdx.x;   // 16384 threads
    int k = i >> 7, n = i & 127;
    Wt[n * 128 + k] = __float2half(W[i]);
}

// ---- MFMA GEMM [nrows,128]@[128,128] -> fp16, fused attention logits ----
// wave handles 16 rows x 128 cols; A from Xf (fp32) or Xh (fp16); B from Wt (L1/L2).
__global__ __launch_bounds__(256)
void gemm_mfma_k(const float* __restrict__ Xf, const __half* __restrict__ Xh,
                 const __half* __restrict__ Wt, __half* __restrict__ Yh, int nrows,
                 const float* __restrict__ att_s, const float* __restrict__ att_d,
                 float* __restrict__ asb, float* __restrict__ adb) {
    int lane = threadIdx.x & 63;
    int wid  = threadIdx.x >> 6;
    int n = lane & 15, quad = lane >> 4;
    float atts_r[8], attd_r[8];
#pragma unroll
    for (int t = 0; t < 8; ++t) {
        atts_r[t] = att_s[t * 16 + n];
        attd_r[t] = att_d[t * 16 + n];
    }
    for (int row0 = (blockIdx.x * 4 + wid) * 16; row0 < nrows; row0 += gridDim.x * 64) {
        float4_t acc[8];
#pragma unroll
        for (int t = 0; t < 8; ++t) acc[t] = (float4_t){0.f, 0.f, 0.f, 0.f};
        int rA = row0 + n; if (rA >= nrows) rA = nrows - 1;
#pragma unroll
        for (int ch = 0; ch < 4; ++ch) {
            half8_t a;
            if (Xh) {
                a = *(const half8_t*)(Xh + (size_t)rA * 128 + ch * 32 + quad * 8);
            } else {
                const float* xp = Xf + (size_t)rA * 128 + ch * 32 + quad * 8;
                float4 f0 = *(const float4*)xp;
                float4 f1 = *(const float4*)(xp + 4);
                a = (half8_t){(_Float16)f0.x, (_Float16)f0.y, (_Float16)f0.z, (_Float16)f0.w,
                              (_Float16)f1.x, (_Float16)f1.y, (_Float16)f1.z, (_Float16)f1.w};
            }
#pragma unroll
            for (int t = 0; t < 8; ++t) {
                half8_t b = *(const half8_t*)(Wt + (t * 16 + n) * 128 + ch * 32 + quad * 8);
                acc[t] = __builtin_amdgcn_mfma_f32_16x16x32_f16(a, b, acc[t], 0, 0, 0);
            }
        }
        // C store (fp16): col = t*16 + n, row = quad*4 + rg
#pragma unroll
        for (int rg = 0; rg < 4; ++rg) {
            int row = row0 + quad * 4 + rg;
            if (row < nrows) {
                __half* yp = Yh + (size_t)row * 128 + n;
#pragma unroll
                for (int t = 0; t < 8; ++t)
                    yp[t * 16] = __float2half(acc[t][rg]);
            }
        }
        // fused alpha: reduce acc * att over the 16 col-lanes of each quad
#pragma unroll
        for (int rg = 0; rg < 4; ++rg) {
            float ps[4], pd[4];
#pragma unroll
            for (int h = 0; h < 4; ++h) {
                ps[h] = acc[2*h][rg] * atts_r[2*h] + acc[2*h+1][rg] * atts_r[2*h+1];
                pd[h] = acc[2*h][rg] * attd_r[2*h] + acc[2*h+1][rg] * attd_r[2*h+1];
#pragma unroll
                for (int mask = 1; mask < 16; mask <<= 1) {
                    ps[h] += __shfl_xor(ps[h], mask, 64);
                    pd[h] += __shfl_xor(pd[h], mask, 64);
                }
            }
            int row = row0 + quad * 4 + rg;
            if (n == 0 && row < nrows) {
#pragma unroll
                for (int h = 0; h < 4; ++h) {
                    asb[row * 4 + h] = ps[h];
                    adb[row * 4 + h] = pd[h];
                }
            }
        }
    }
}

// ---- fused softmax + aggregation + bias + ELU (+ optional layer-3 projection) ----
// half-wave (32 lanes) per node, 4 channels per lane
__global__ __launch_bounds__(256)
void agg_k(const __half* __restrict__ Hh, const float* __restrict__ asb,
           const float* __restrict__ adb, const int* __restrict__ rp,
           const int* __restrict__ csr, const float* __restrict__ bias,
           __half* __restrict__ Y,
           const float* __restrict__ W3, const float* __restrict__ s3w,
           const float* __restrict__ d3w, float* __restrict__ h3,
           float* __restrict__ as3, float* __restrict__ ad3) {
    int lane = threadIdx.x & 63;
    int hw = lane >> 5;
    int l  = lane & 31;                   // owns channels l*4 .. l*4+3
    int n = blockIdx.x * 8 + (threadIdx.x >> 6) * 2 + hw;
    if (n >= NN) return;
    int hd = l >> 3;
    float ad = adb[n * 4 + hd];
    float acc0 = 0.f, acc1 = 0.f, acc2 = 0.f, acc3 = 0.f, den = 0.f;
    int e = rp[n], end = rp[n + 1], last = end - 1;
    for (int base = e; base < end; base += 8) {
        int s[8]; float a[8]; float2 hraw[8];
#pragma unroll
        for (int j = 0; j < 8; ++j) {
            int i = base + j;
            s[j] = csr[i <= last ? i : last];
        }
#pragma unroll
        for (int j = 0; j < 8; ++j) a[j] = asb[s[j] * 4 + hd] + ad;
#pragma unroll
        for (int j = 0; j < 8; ++j)
            hraw[j] = ((const float2*)(Hh + (size_t)s[j] * 128))[l];
#pragma unroll
        for (int j = 0; j < 8; ++j) {
            float w = __expf(leaky(a[j]));
            w = (base + j <= last) ? w : 0.f;
            den += w;
            const __half2* hp = (const __half2*)&hraw[j];
            float2 f01 = __half22float2(hp[0]);
            float2 f23 = __half22float2(hp[1]);
            acc0 += w * f01.x; acc1 += w * f01.y;
            acc2 += w * f23.x; acc3 += w * f23.y;
        }
    }
    float4 bv = ((const float4*)bias)[l];
    float inv = 1.f / den;
    float o0 = elu_f(acc0 * inv + bv.x);
    float o1 = elu_f(acc1 * inv + bv.y);
    float o2 = elu_f(acc2 * inv + bv.z);
    float o3 = elu_f(acc3 * inv + bv.w);
    if (!W3) {
        half4 hv;
        hv.a = __floats2half2_rn(o0, o1);
        hv.b = __floats2half2_rn(o2, o3);
        ((half4*)(Y + (size_t)n * 128))[l] = hv;
    } else {
        float4 wa = ((const float4*)W3)[l * 2];
        float4 wb = ((const float4*)W3)[l * 2 + 1];
        float p0 = o0 * wa.x + o1 * wa.z + o2 * wb.x + o3 * wb.z;
        float p1 = o0 * wa.y + o1 * wa.w + o2 * wb.y + o3 * wb.w;
        for (int off = 16; off > 0; off >>= 1) {
            p0 += __shfl_down(p0, off, 32);
            p1 += __shfl_down(p1, off, 32);
        }
        if (l == 0) {
            h3[n * 2 + 0] = p0;
            h3[n * 2 + 1] = p1;
            as3[n] = p0 * s3w[0] + p1 * s3w[1];
            ad3[n] = p0 * d3w[0] + p1 * d3w[1];
        }
    }
}

// ---- layer-3 aggregation + log_softmax ----
__global__ void l3agg_k(const float* __restrict__ h3, const float* __restrict__ as3,
                        const float* __restrict__ ad3, const int* __restrict__ rp,
                        const int* __restrict__ csr, const float* __restrict__ b3,
                        float* __restrict__ out) {
    int n = blockIdx.x * blockDim.x + threadIdx.x;
    if (n >= NN) return;
    const float2* h2 = (const float2*)h3;
    float adn = ad3[n];
    float den = 0.f, a0 = 0.f, a1 = 0.f;
    int e = rp[n], end = rp[n + 1], last = end - 1;
    for (int base = e; base < end; base += 4) {
        int s[4]; float al[4]; float2 g[4];
#pragma unroll
        for (int j = 0; j < 4; ++j) {
            int i = base + j;
            s[j] = csr[i <= last ? i : last];
        }
#pragma unroll
        for (int j = 0; j < 4; ++j) al[j] = as3[s[j]] + adn;
#pragma unroll
        for (int j = 0; j < 4; ++j) g[j] = h2[s[j]];
#pragma unroll
        for (int j = 0; j < 4; ++j) {
            float w = __expf(leaky(al[j]));
            w = (base + j <= last) ? w : 0.f;
            den += w;
            a0 += w * g[j].x;
            a1 += w * g[j].y;
        }
    }
    float o0 = a0 / den + b3[0];
    float o1 = a1 / den + b3[1];
    float m = fmaxf(o0, o1);
    float lse = m + logf(__expf(o0 - m) + __expf(o1 - m));
    out[n * 2 + 0] = o0 - lse;
    out[n * 2 + 1] = o1 - lse;
}

extern "C" void kernel_launch(void* const* d_in, const int* in_sizes, int n_in,
                              void* d_out, int out_size, void* d_ws, size_t ws_size,
                              hipStream_t stream) {
    const float* x   = (const float*)d_in[0];
    const int*   ei  = (const int*)d_in[1];
    const float* W1  = (const float*)d_in[2];
    const float* as1 = (const float*)d_in[3];
    const float* ad1 = (const float*)d_in[4];
    const float* b1  = (const float*)d_in[5];
    const float* W2  = (const float*)d_in[6];
    const float* as2 = (const float*)d_in[7];
    const float* ad2 = (const float*)d_in[8];
    const float* b2  = (const float*)d_in[9];
    const float* W3  = (const float*)d_in[10];
    const float* s3w = (const float*)d_in[11];
    const float* d3w = (const float*)d_in[12];
    const float* b3  = (const float*)d_in[13];
    float* out = (float*)d_out;

    char* ws = (char*)d_ws;
    size_t off = 0;
    auto alloc = [&](size_t bytes) -> char* {
        char* p = ws + off;
        off = (off + bytes + 255) & ~(size_t)255;
        return p;
    };
    __half* hA    = (__half*)alloc((size_t)NN * 128 * 2);   // fp16 gather table
    __half* hBh   = (__half*)alloc((size_t)NN * 128 * 2);   // agg1 out (gemm2 in, fp16)
    float* asb    = (float*)alloc((size_t)NN * 4 * 4);
    float* adb    = (float*)alloc((size_t)NN * 4 * 4);
    int*   rp     = (int*)alloc((size_t)(NN + 1) * 4);
    int*   counts = (int*)alloc((size_t)NN * 4);
    int*   csr    = (int*)alloc((size_t)ET * 4);
    int*   rank   = (int*)alloc((size_t)ET * 4);
    int*   bsums  = (int*)alloc((size_t)NBLK * 4);
    __half* Wt1   = (__half*)alloc(128 * 128 * 2);
    __half* Wt2   = (__half*)alloc(128 * 128 * 2);
    float* h3     = (float*)alloc((size_t)NN * 2 * 4);
    float* s3     = (float*)alloc((size_t)NN * 4);
    float* d3     = (float*)alloc((size_t)NN * 4);

    // weight transposes (fp16), independent of everything else
    wt_k<<<64, 256, 0, stream>>>(W1, Wt1);
    wt_k<<<64, 256, 0, stream>>>(W2, Wt2);

    // CSR by destination (shared by all 3 layers)
    hipMemsetAsync(counts, 0, (size_t)NN * 4, stream);
    hist_k<<<(ET + 255) / 256, 256, 0, stream>>>(ei, counts, rank);
    scan1_k<<<NBLK, 256, 0, stream>>>(counts, rp, bsums);
    scan2_k<<<1, 64, 0, stream>>>(bsums, rp);
    scan3_k<<<NBLK, 256, 0, stream>>>(rp, bsums);
    scatter_k<<<(ET + 255) / 256, 256, 0, stream>>>(ei, rp, rank, csr);

    // Layer 1 (alpha fused into gemm epilogue)
    gemm_mfma_k<<<(NN + 63) / 64, 256, 0, stream>>>(x, nullptr, Wt1, hA, NN,
                                                    as1, ad1, asb, adb);
    agg_k<<<(NN + 7) / 8, 256, 0, stream>>>(hA, asb, adb, rp, csr, b1, hBh,
                                            nullptr, nullptr, nullptr,
                                            nullptr, nullptr, nullptr);

    // Layer 2 (+ fused layer-3 projection/logits in agg epilogue)
    gemm_mfma_k<<<(NN + 63) / 64, 256, 0, stream>>>(nullptr, hBh, Wt2, hA, NN,
                                                    as2, ad2, asb, adb);
    agg_k<<<(NN + 7) / 8, 256, 0, stream>>>(hA, asb, adb, rp, csr, b2, nullptr,
                                            W3, s3w, d3w, h3, s3, d3);

    // Layer 3 aggregation + log_softmax
    l3agg_k<<<(NN + 255) / 256, 256, 0, stream>>>(h3, s3, d3, rp, csr, b3, out);
}